// Round 5
// baseline (34.121 us; speedup 1.0000x reference)
//
#include <hip/hip_runtime.h>
#include <math.h>

// Problem constants (match reference)
constexpr int   BB    = 32;
constexpr int   NF    = 500;
constexpr int   FS    = 240;
constexpr int   TT    = NF * FS;     // 120000
constexpr int   HH    = 8;
constexpr float ALPHA = 0.1f;

constexpr int SPT = 8;               // samples per thread (240 % 8 == 0)
constexpr int BLK = 256;

typedef float f32x4 __attribute__((ext_vector_type(4)));   // for nontemporal builtins

__device__ __forceinline__ float sin_rev(float fr) {
    // fr in [-0.5, 0.5] revolutions; v_sin_f32: D = sin(S0 * 2pi)
#if __has_builtin(__builtin_amdgcn_sinf)
    return __builtin_amdgcn_sinf(fr);
#else
    return __sinf(fr * 6.28318530717958647692f);
#endif
}

__device__ __forceinline__ float tanh_fast(float x) {
    // tanh(x) = 1 - 2/(e^{2x}+1); exp saturation gives correct +-1 limits.
    const float e = __expf(2.0f * x);
#if __has_builtin(__builtin_amdgcn_rcpf)
    const float r = __builtin_amdgcn_rcpf(e + 1.0f);
#else
    const float r = 1.0f / (e + 1.0f);
#endif
    return fmaf(-2.0f, r, 1.0f);
}

// ---------------------------------------------------------------------------
// Fused kernel. All 256 threads cooperate on the frame-phase scan
// (2 frames/thread, wave-scan + cross-wave LDS combine), then each thread
// synthesizes 8 consecutive samples (never crossing a frame boundary).
// ---------------------------------------------------------------------------
__global__ __launch_bounds__(BLK) void synth_fused(const float* __restrict__ f0s,
                                                   const float* __restrict__ phi,
                                                   const float* __restrict__ amp,
                                                   const float* __restrict__ noise,
                                                   float* __restrict__ out) {
    const int b    = blockIdx.y;
    const int tid  = threadIdx.x;
    const int lane = tid & 63;
    const int wv   = tid >> 6;

    __shared__ float2 sfr[NF];          // {frac(prefix_rev) at frame start, dphi_rev}
    __shared__ double wtot[BLK / 64];   // per-wave scan totals

    // ---- cooperative frame-level phase prefix scan (f64, revolutions) ----
    {
        const float  TWO_PI_F = 6.28318530717958647692f;
        const double INV_2PI  = 0.15915494309189533576;

        const int fi = 2 * tid;
        double d0 = 0.0, d1 = 0.0;
        if (fi < NF) {
            const float dphi = (TWO_PI_F * f0s[b * NF + fi]) / 24000.0f;  // f32, np op order
            d0 = (double)dphi * INV_2PI;
        }
        if (fi + 1 < NF) {
            const float dphi = (TWO_PI_F * f0s[b * NF + fi + 1]) / 24000.0f;
            d1 = (double)dphi * INV_2PI;
        }

        const double s = (d0 + d1) * 240.0;   // revolutions across this thread's 2 frames
        double run = s;
        for (int delta = 1; delta < 64; delta <<= 1) {
            const double o = __shfl_up(run, delta, 64);
            if (lane >= delta) run += o;
        }
        if (lane == 63) wtot[wv] = run;
        __syncthreads();

        double woff = 0.0;
        for (int w2 = 0; w2 < wv; ++w2) woff += wtot[w2];
        double pref = woff + (run - s);       // exclusive prefix at frame fi

        if (fi < NF) {
            const double fx0 = pref - rint(pref);
            sfr[fi] = make_float2((float)fx0, (float)d0);
            if (fi + 1 < NF) {
                const double p1  = pref + d0 * 240.0;
                const double fx1 = p1 - rint(p1);
                sfr[fi + 1] = make_float2((float)fx1, (float)d1);
            }
        }
        __syncthreads();
    }

    // ---- per-thread synth of 8 consecutive samples ----
    const int t = (blockIdx.x * BLK + tid) * SPT;
    if (t >= TT) return;

    const int f = t / FS;
    const int j = t - f * FS;                 // multiple of 8, within one frame
    const size_t base = (size_t)b * TT + t;

    const float2 fd = sfr[f];
    const float  dr = fd.y;
    const bool   voiced = (dr > 0.0f);

    float cs[SPT];
    cs[0] = fd.x + (float)(j + 1) * dr;       // inclusive cumsum semantics
#pragma unroll
    for (int e = 1; e < SPT; ++e) cs[e] = cs[e - 1] + dr;

    const float INV2PIf = 0.15915494309189533576f;

    float sdot[SPT], ndot[SPT];
#pragma unroll
    for (int e = 0; e < SPT; ++e) { sdot[e] = 0.f; ndot[e] = 0.f; }

#pragma unroll
    for (int h = 0; h < HH; ++h) {
        const float a  = amp[h];
        const float ph = phi[h] * INV2PIf;
        const float kf = (float)(h + 1);

        const f32x4* p = reinterpret_cast<const f32x4*>(
            noise + (size_t)h * (BB * (size_t)TT) + base);
        const f32x4 m0 = __builtin_nontemporal_load(p);
        const f32x4 m1 = __builtin_nontemporal_load(p + 1);

        ndot[0] = fmaf(a, m0.x, ndot[0]);
        ndot[1] = fmaf(a, m0.y, ndot[1]);
        ndot[2] = fmaf(a, m0.z, ndot[2]);
        ndot[3] = fmaf(a, m0.w, ndot[3]);
        ndot[4] = fmaf(a, m1.x, ndot[4]);
        ndot[5] = fmaf(a, m1.y, ndot[5]);
        ndot[6] = fmaf(a, m1.z, ndot[6]);
        ndot[7] = fmaf(a, m1.w, ndot[7]);

#pragma unroll
        for (int e = 0; e < SPT; ++e) {
            const float r  = fmaf(kf, cs[e], ph);   // k*cs + phi (matches ref's k*cs)
            const float fx = r - rintf(r);          // reduce to [-0.5, 0.5] rev
            sdot[e] = fmaf(a, sin_rev(fx), sdot[e]);
        }
    }

    const float a8 = amp[HH];
    const float UV = (float)(0.1 / (3.0 * 0.003));  // ALPHA / (3*SIGMA)

    float tmp[SPT];
#pragma unroll
    for (int e = 0; e < SPT; ++e) {
        const float x = voiced ? fmaf(ALPHA, sdot[e], ndot[e]) : UV * ndot[e];
        tmp[e] = tanh_fast(x + a8);
    }

    f32x4* ov = reinterpret_cast<f32x4*>(out + base);
    f32x4 o0; o0.x = tmp[0]; o0.y = tmp[1]; o0.z = tmp[2]; o0.w = tmp[3];
    f32x4 o1; o1.x = tmp[4]; o1.y = tmp[5]; o1.z = tmp[6]; o1.w = tmp[7];
    __builtin_nontemporal_store(o0, ov);
    __builtin_nontemporal_store(o1, ov + 1);
}

// ---------------------------------------------------------------------------
extern "C" void kernel_launch(void* const* d_in, const int* in_sizes, int n_in,
                              void* d_out, int out_size, void* d_ws, size_t ws_size,
                              hipStream_t stream) {
    const float* f0s   = (const float*)d_in[0];   // [32, 500]
    const float* phi   = (const float*)d_in[1];   // [8]
    const float* amp   = (const float*)d_in[2];   // [9]
    const float* noise = (const float*)d_in[3];   // [8, 32, 120000]
    float* out = (float*)d_out;                   // [32, 120000]

    const int blocks_x = (TT / SPT + BLK - 1) / BLK;   // 59
    dim3 grid(blocks_x, BB);
    synth_fused<<<grid, BLK, 0, stream>>>(f0s, phi, amp, noise, out);
}

// Round 6
// 28.232 us; speedup vs baseline: 1.2086x; 1.2086x over previous
//
#include <hip/hip_runtime.h>
#include <math.h>

// Problem constants (match reference)
constexpr int   BB    = 32;
constexpr int   NF    = 500;
constexpr int   FS    = 240;
constexpr int   TT    = NF * FS;     // 120000
constexpr int   HH    = 8;
constexpr float ALPHA = 0.1f;

constexpr int SPT = 8;               // samples per thread (240 % 8 == 0)
constexpr int BLK = 256;

__device__ __forceinline__ float sin_rev(float fr) {
    // fr in [-0.5, 0.5] revolutions; v_sin_f32: D = sin(S0 * 2pi)
#if __has_builtin(__builtin_amdgcn_sinf)
    return __builtin_amdgcn_sinf(fr);
#else
    return __sinf(fr * 6.28318530717958647692f);
#endif
}

__device__ __forceinline__ float tanh_fast(float x) {
    // tanh(x) = 1 - 2/(e^{2x}+1); exp saturation gives correct +-1 limits.
    const float e = __expf(2.0f * x);
#if __has_builtin(__builtin_amdgcn_rcpf)
    const float r = __builtin_amdgcn_rcpf(e + 1.0f);
#else
    const float r = 1.0f / (e + 1.0f);
#endif
    return fmaf(-2.0f, r, 1.0f);
}

// ---------------------------------------------------------------------------
// Fused kernel. All 256 threads cooperate on the frame-phase scan
// (2 frames/thread, wave-scan + cross-wave LDS combine), then each thread
// synthesizes 8 consecutive samples (never crossing a frame boundary).
// Plain cached loads/stores — nontemporal hints measured -4 us (R4).
// ---------------------------------------------------------------------------
__global__ __launch_bounds__(BLK) void synth_fused(const float* __restrict__ f0s,
                                                   const float* __restrict__ phi,
                                                   const float* __restrict__ amp,
                                                   const float* __restrict__ noise,
                                                   float* __restrict__ out) {
    const int b    = blockIdx.y;
    const int tid  = threadIdx.x;
    const int lane = tid & 63;
    const int wv   = tid >> 6;

    __shared__ float2 sfr[NF];          // {frac(prefix_rev) at frame start, dphi_rev}
    __shared__ double wtot[BLK / 64];   // per-wave scan totals

    // ---- cooperative frame-level phase prefix scan (f64, revolutions) ----
    {
        const float  TWO_PI_F = 6.28318530717958647692f;
        const double INV_2PI  = 0.15915494309189533576;

        const int fi = 2 * tid;
        double d0 = 0.0, d1 = 0.0;
        if (fi < NF) {
            const float dphi = (TWO_PI_F * f0s[b * NF + fi]) / 24000.0f;  // f32, np op order
            d0 = (double)dphi * INV_2PI;
        }
        if (fi + 1 < NF) {
            const float dphi = (TWO_PI_F * f0s[b * NF + fi + 1]) / 24000.0f;
            d1 = (double)dphi * INV_2PI;
        }

        const double s = (d0 + d1) * 240.0;   // revolutions across this thread's 2 frames
        double run = s;
        for (int delta = 1; delta < 64; delta <<= 1) {
            const double o = __shfl_up(run, delta, 64);
            if (lane >= delta) run += o;
        }
        if (lane == 63) wtot[wv] = run;
        __syncthreads();

        double woff = 0.0;
        for (int w2 = 0; w2 < wv; ++w2) woff += wtot[w2];
        double pref = woff + (run - s);       // exclusive prefix at frame fi

        if (fi < NF) {
            const double fx0 = pref - rint(pref);
            sfr[fi] = make_float2((float)fx0, (float)d0);
            if (fi + 1 < NF) {
                const double p1  = pref + d0 * 240.0;
                const double fx1 = p1 - rint(p1);
                sfr[fi + 1] = make_float2((float)fx1, (float)d1);
            }
        }
        __syncthreads();
    }

    // ---- per-thread synth of 8 consecutive samples ----
    const int t = (blockIdx.x * BLK + tid) * SPT;
    if (t >= TT) return;

    const int f = t / FS;
    const int j = t - f * FS;                 // multiple of 8, within one frame
    const size_t base = (size_t)b * TT + t;

    const float2 fd = sfr[f];
    const float  dr = fd.y;
    const bool   voiced = (dr > 0.0f);

    float cs[SPT];
    cs[0] = fd.x + (float)(j + 1) * dr;       // inclusive cumsum semantics
#pragma unroll
    for (int e = 1; e < SPT; ++e) cs[e] = cs[e - 1] + dr;

    const float INV2PIf = 0.15915494309189533576f;

    float sdot[SPT], ndot[SPT];
#pragma unroll
    for (int e = 0; e < SPT; ++e) { sdot[e] = 0.f; ndot[e] = 0.f; }

#pragma unroll
    for (int h = 0; h < HH; ++h) {
        const float a  = amp[h];
        const float ph = phi[h] * INV2PIf;
        const float kf = (float)(h + 1);

        const float4* p = reinterpret_cast<const float4*>(
            noise + (size_t)h * (BB * (size_t)TT) + base);
        const float4 m0 = p[0];
        const float4 m1 = p[1];

        ndot[0] = fmaf(a, m0.x, ndot[0]);
        ndot[1] = fmaf(a, m0.y, ndot[1]);
        ndot[2] = fmaf(a, m0.z, ndot[2]);
        ndot[3] = fmaf(a, m0.w, ndot[3]);
        ndot[4] = fmaf(a, m1.x, ndot[4]);
        ndot[5] = fmaf(a, m1.y, ndot[5]);
        ndot[6] = fmaf(a, m1.z, ndot[6]);
        ndot[7] = fmaf(a, m1.w, ndot[7]);

#pragma unroll
        for (int e = 0; e < SPT; ++e) {
            const float r  = fmaf(kf, cs[e], ph);   // k*cs + phi (matches ref's k*cs)
            const float fx = r - rintf(r);          // reduce to [-0.5, 0.5] rev
            sdot[e] = fmaf(a, sin_rev(fx), sdot[e]);
        }
    }

    const float a8 = amp[HH];
    const float UV = (float)(0.1 / (3.0 * 0.003));  // ALPHA / (3*SIGMA)

    float tmp[SPT];
#pragma unroll
    for (int e = 0; e < SPT; ++e) {
        const float x = voiced ? fmaf(ALPHA, sdot[e], ndot[e]) : UV * ndot[e];
        tmp[e] = tanh_fast(x + a8);
    }

    float4* ov = reinterpret_cast<float4*>(out + base);
    ov[0] = make_float4(tmp[0], tmp[1], tmp[2], tmp[3]);
    ov[1] = make_float4(tmp[4], tmp[5], tmp[6], tmp[7]);
}

// ---------------------------------------------------------------------------
extern "C" void kernel_launch(void* const* d_in, const int* in_sizes, int n_in,
                              void* d_out, int out_size, void* d_ws, size_t ws_size,
                              hipStream_t stream) {
    const float* f0s   = (const float*)d_in[0];   // [32, 500]
    const float* phi   = (const float*)d_in[1];   // [8]
    const float* amp   = (const float*)d_in[2];   // [9]
    const float* noise = (const float*)d_in[3];   // [8, 32, 120000]
    float* out = (float*)d_out;                   // [32, 120000]

    const int blocks_x = (TT / SPT + BLK - 1) / BLK;   // 59
    dim3 grid(blocks_x, BB);
    synth_fused<<<grid, BLK, 0, stream>>>(f0s, phi, amp, noise, out);
}

// Round 7
// 27.927 us; speedup vs baseline: 1.2218x; 1.0109x over previous
//
#include <hip/hip_runtime.h>
#include <math.h>

// Problem constants (match reference)
constexpr int   BB    = 32;
constexpr int   NF    = 500;
constexpr int   FS    = 240;
constexpr int   TT    = NF * FS;     // 120000 samples per row
constexpr int   HH    = 8;
constexpr float ALPHA = 0.1f;

constexpr int SPT = 4;               // samples per thread (240 % 4 == 0)
constexpr int BLK = 256;
// 32 rows * 120000 samples / (256*4) = 3750 blocks, exact cover, no tail.

__device__ __forceinline__ float sin_rev(float fr) {
    // fr in [-0.5, 0.5] revolutions; v_sin_f32: D = sin(S0 * 2pi)
#if __has_builtin(__builtin_amdgcn_sinf)
    return __builtin_amdgcn_sinf(fr);
#else
    return __sinf(fr * 6.28318530717958647692f);
#endif
}

__device__ __forceinline__ float tanh_fast(float x) {
    // tanh(x) = 1 - 2/(e^{2x}+1); exp saturation gives correct +-1 limits.
    const float e = __expf(2.0f * x);
#if __has_builtin(__builtin_amdgcn_rcpf)
    const float r = __builtin_amdgcn_rcpf(e + 1.0f);
#else
    const float r = 1.0f / (e + 1.0f);
#endif
    return fmaf(-2.0f, r, 1.0f);
}

// ---------------------------------------------------------------------------
// Flat-grid fused kernel. Block bid covers samples [bid*1024, bid*1024+1024)
// of the flattened [32 x 120000] output. All 256 threads cooperate on the
// frame-phase scan for the block's first row b0; blocks that span a row
// boundary (31 of 3750) additionally need frames 0..4 of row b1, whose
// cumsum prefix starts at ZERO -> thread 0 computes them directly.
// ---------------------------------------------------------------------------
__global__ __launch_bounds__(BLK) void synth_fused(const float* __restrict__ f0s,
                                                   const float* __restrict__ phi,
                                                   const float* __restrict__ amp,
                                                   const float* __restrict__ noise,
                                                   float* __restrict__ out) {
    const int bid  = blockIdx.x;
    const int tid  = threadIdx.x;
    const int lane = tid & 63;
    const int wv   = tid >> 6;

    const int s_first = bid * (BLK * SPT);              // first sample of block
    const int b0 = s_first / TT;
    const int b1 = (s_first + BLK * SPT - 1) / TT;      // row of last sample

    __shared__ float2 sfr[NF];          // row b0: {frac(prefix_rev), dphi_rev}
    __shared__ float2 sfr1[8];          // row b1: first frames (prefix starts at 0)
    __shared__ double wtot[BLK / 64];   // per-wave scan totals

    const float  TWO_PI_F = 6.28318530717958647692f;
    const double INV_2PI  = 0.15915494309189533576;

    // ---- cooperative frame-level phase prefix scan for row b0 ----
    {
        const int fi = 2 * tid;
        double d0 = 0.0, d1 = 0.0;
        if (fi < NF) {
            const float dphi = (TWO_PI_F * f0s[b0 * NF + fi]) / 24000.0f;  // f32, np op order
            d0 = (double)dphi * INV_2PI;
        }
        if (fi + 1 < NF) {
            const float dphi = (TWO_PI_F * f0s[b0 * NF + fi + 1]) / 24000.0f;
            d1 = (double)dphi * INV_2PI;
        }

        const double s = (d0 + d1) * 240.0;   // revolutions across this thread's 2 frames
        double run = s;
        for (int delta = 1; delta < 64; delta <<= 1) {
            const double o = __shfl_up(run, delta, 64);
            if (lane >= delta) run += o;
        }
        if (lane == 63) wtot[wv] = run;
        __syncthreads();

        double woff = 0.0;
        for (int w2 = 0; w2 < wv; ++w2) woff += wtot[w2];
        double pref = woff + (run - s);       // exclusive prefix at frame fi

        if (fi < NF) {
            const double fx0 = pref - rint(pref);
            sfr[fi] = make_float2((float)fx0, (float)d0);
            if (fi + 1 < NF) {
                const double p1  = pref + d0 * 240.0;
                const double fx1 = p1 - rint(p1);
                sfr[fi + 1] = make_float2((float)fx1, (float)d1);
            }
        }

        // boundary rows: frames 0..4 of b1 (cumsum restarts at 0 per row)
        if (b1 != b0 && tid == 0) {
            double acc = 0.0;
#pragma unroll
            for (int g = 0; g < 8; ++g) {
                const float dphi = (TWO_PI_F * f0s[b1 * NF + g]) / 24000.0f;
                const double dg  = (double)dphi * INV_2PI;
                const double fx  = acc - rint(acc);
                sfr1[g] = make_float2((float)fx, (float)dg);
                acc += dg * 240.0;
            }
        }
        __syncthreads();
    }

    // ---- per-thread synth of 4 consecutive samples ----
    const int s = s_first + tid * SPT;        // global flat sample index
    const int b = s / TT;
    const int t = s - b * TT;
    const int f = t / FS;
    const int j = t - f * FS;                 // multiple of 4, within one frame
    const size_t base = (size_t)s;            // == b*TT + t in flat layout

    const float2 fd = (b == b0) ? sfr[f] : sfr1[f];
    const float  dr = fd.y;
    const bool   voiced = (dr > 0.0f);

    float cs[SPT];
    cs[0] = fd.x + (float)(j + 1) * dr;       // inclusive cumsum semantics
#pragma unroll
    for (int e = 1; e < SPT; ++e) cs[e] = cs[e - 1] + dr;

    const float INV2PIf = 0.15915494309189533576f;

    float sdot[SPT], ndot[SPT];
#pragma unroll
    for (int e = 0; e < SPT; ++e) { sdot[e] = 0.f; ndot[e] = 0.f; }

#pragma unroll
    for (int h = 0; h < HH; ++h) {
        const float a  = amp[h];
        const float ph = phi[h] * INV2PIf;
        const float kf = (float)(h + 1);

        const float4 m0 = *reinterpret_cast<const float4*>(
            noise + (size_t)h * (BB * (size_t)TT) + base);

        ndot[0] = fmaf(a, m0.x, ndot[0]);
        ndot[1] = fmaf(a, m0.y, ndot[1]);
        ndot[2] = fmaf(a, m0.z, ndot[2]);
        ndot[3] = fmaf(a, m0.w, ndot[3]);

#pragma unroll
        for (int e = 0; e < SPT; ++e) {
            const float r  = fmaf(kf, cs[e], ph);   // k*cs + phi
            const float fx = r - rintf(r);          // reduce to [-0.5, 0.5] rev
            sdot[e] = fmaf(a, sin_rev(fx), sdot[e]);
        }
    }

    const float a8 = amp[HH];
    const float UV = (float)(0.1 / (3.0 * 0.003));  // ALPHA / (3*SIGMA)

    float tmp[SPT];
#pragma unroll
    for (int e = 0; e < SPT; ++e) {
        const float x = voiced ? fmaf(ALPHA, sdot[e], ndot[e]) : UV * ndot[e];
        tmp[e] = tanh_fast(x + a8);
    }

    *reinterpret_cast<float4*>(out + base) =
        make_float4(tmp[0], tmp[1], tmp[2], tmp[3]);
}

// ---------------------------------------------------------------------------
extern "C" void kernel_launch(void* const* d_in, const int* in_sizes, int n_in,
                              void* d_out, int out_size, void* d_ws, size_t ws_size,
                              hipStream_t stream) {
    const float* f0s   = (const float*)d_in[0];   // [32, 500]
    const float* phi   = (const float*)d_in[1];   // [8]
    const float* amp   = (const float*)d_in[2];   // [9]
    const float* noise = (const float*)d_in[3];   // [8, 32, 120000]
    float* out = (float*)d_out;                   // [32, 120000]

    const int nblocks = (BB * TT) / (BLK * SPT);  // 3750, exact
    synth_fused<<<nblocks, BLK, 0, stream>>>(f0s, phi, amp, noise, out);
}